// Round 10
// baseline (270.077 us; speedup 1.0000x reference)
//
#include <hip/hip_runtime.h>
#include <hip/hip_bf16.h>

#define N_TOK  4096
#define HD     512   // H * 64
#define NH     8
#define NSPLIT 4
#define QBLK   128
#define NT     ((N_TOK / NSPLIT) / 64)

typedef short v8s __attribute__((ext_vector_type(8)));
typedef float v4f __attribute__((ext_vector_type(4)));
typedef float v16f __attribute__((ext_vector_type(16)));
typedef unsigned short u16;

#define QSCALE   0.18033688011112042f   // log2(e)/8  (folded into q at projection)
#define ADJ2     0.14426950408889634f   // 0.1*log2(e) (folded into E=exp2(ADJ2*adj))
// u8 encoding of E-1: E in [1, e^0.1]; enc = (E-1)*EC, E = 1 + enc*ER
#define EC 2424.6f
#define ER 4.1244e-4f
// minimax cubic for e^x on [0,1]: max abs err ~5.5e-4 (<< bf16 P quantization 4e-3)
#define EA0 0.999410f
#define EA1 1.016220f
#define EA2 0.423120f
#define EA3 0.279120f

__device__ __forceinline__ float bf2f(u16 x) {
  union { unsigned int u; float f; } c; c.u = ((unsigned int)x) << 16; return c.f;
}
__device__ __forceinline__ u16 f2bf(float f) {
  union { float f; unsigned int u; } c; c.f = f;
  return (u16)((c.u + 0x7fffu + ((c.u >> 16) & 1u)) >> 16);
}
__device__ __forceinline__ float fast_exp2(float x) {
#if __has_builtin(__builtin_amdgcn_exp2f)
  return __builtin_amdgcn_exp2f(x);
#else
  return exp2f(x);
#endif
}
__device__ __forceinline__ unsigned int pk_bf16(float a, float b) {
  union { __hip_bfloat162 h; unsigned int u; } c;
  c.h = __float22bfloat162_rn(make_float2(a, b));
  return c.u;
}

// async global->LDS, 16B per lane; LDS dest is wave-uniform base + lane*16
typedef __attribute__((address_space(1))) const char gchar;
typedef __attribute__((address_space(3))) char lchar;
__device__ __forceinline__ void glds16(const void* g, void* l) {
  __builtin_amdgcn_global_load_lds((gchar*)g, (lchar*)l, 16, 0, 0);
}
// a' = [a_lo | b_lo], b' = [a_hi | b_hi]
__device__ __forceinline__ void plswap(unsigned int& a, unsigned int& b) {
  asm volatile("v_permlane32_swap_b32 %0, %1" : "+v"(a), "+v"(b));
}

// ---------- inline dtype detect: true -> inputs are fp32 (read from Q's first 128 u16) ----------
__device__ __forceinline__ bool detect_f32(const u16* __restrict__ q) {
  int l = threadIdx.x & 63;
  u16 e = q[2 * l];
  float x = bf2f(e);
  int ex = (e >> 7) & 0xFF;
  float ax = fabsf(x);
  bool ok = (ex != 0xFF) && (ax < 64.f) && (ax > 1e-30f);
  unsigned long long m = __ballot(ok);
  return __popcll(m) < 48;
}
__device__ __forceinline__ float bias_ld(const void* b, int i, bool f32) {
  return f32 ? ((const float*)b)[i] : bf2f(((const u16*)b)[i]);
}

// ---------- adjU8: enc = (exp2(ADJ2*adj) - 1) * EC, one byte per element ----------
__global__ __launch_bounds__(256) void conv_adjE_k(const void* __restrict__ adj, unsigned char* __restrict__ adjU8,
                                                   const u16* __restrict__ Qdet) {
  bool f32 = detect_f32(Qdet);
  int i = blockIdx.x * 256 + threadIdx.x;   // 4 elems/thread, grid covers N*N/4 exactly
  float4 f;
  if (f32) {
    f = ((const float4*)adj)[i];
  } else {
    short4 v = ((const short4*)adj)[i];
    f.x = bf2f((u16)v.x); f.y = bf2f((u16)v.y); f.z = bf2f((u16)v.z); f.w = bf2f((u16)v.w);
  }
  unsigned e0 = (unsigned)fmaf(fast_exp2(f.x * ADJ2), EC, 0.5f - EC);
  unsigned e1 = (unsigned)fmaf(fast_exp2(f.y * ADJ2), EC, 0.5f - EC);
  unsigned e2 = (unsigned)fmaf(fast_exp2(f.z * ADJ2), EC, 0.5f - EC);
  unsigned e3 = (unsigned)fmaf(fast_exp2(f.w * ADJ2), EC, 0.5f - EC);
  e0 = e0 > 255u ? 255u : e0; e1 = e1 > 255u ? 255u : e1;
  e2 = e2 > 255u ? 255u : e2; e3 = e3 > 255u ? 255u : e3;
  ((unsigned*)adjU8)[i] = e0 | (e1 << 8) | (e2 << 16) | (e3 << 24);
}

// ---------- fused convert+transpose for all 4 weights: out[C][R] = bf16(in[R][C]) ----------
__global__ __launch_bounds__(256) void tr_w_k(const void* W0, const void* W1, const void* W2, const void* W3,
                                              u16* t0, u16* t1, u16* t2, u16* t3,
                                              const u16* __restrict__ Qdet) {
  bool f32 = detect_f32(Qdet);
  int z = blockIdx.z;
  const void* in; u16* out; int C;
  if (z == 0)      { in = W0; out = t0; C = 512; }
  else if (z == 1) { in = W1; out = t1; C = 512; }
  else if (z == 2) { in = W2; out = t2; C = 512; }
  else             { in = W3; out = t3; C = 64; if (blockIdx.y) return; }
  const int R = 512;
  __shared__ __align__(16) u16 tile[64][72];
  const int r0 = blockIdx.x * 64, c0 = blockIdx.y * 64;
  const int t = threadIdx.x;
#pragma unroll
  for (int rep = 0; rep < 2; ++rep) {
    int idx = (t + rep * 256) * 8;
    int r = idx >> 6, c = idx & 63;
    if (f32) {
      const float* sp = (const float*)in + (size_t)(r0 + r) * C + (c0 + c);
      float4 a = *(const float4*)sp, b = *(const float4*)(sp + 4);
      uint4 q = make_uint4(pk_bf16(a.x, a.y), pk_bf16(a.z, a.w),
                           pk_bf16(b.x, b.y), pk_bf16(b.z, b.w));
      *(uint4*)&tile[r][c] = q;
    } else {
      *(v8s*)&tile[r][c] = *(const v8s*)((const u16*)in + (size_t)(r0 + r) * C + (c0 + c));
    }
  }
  __syncthreads();
#pragma unroll
  for (int rep = 0; rep < 2; ++rep) {
    int idx = (t + rep * 256) * 8;
    int oc = idx >> 6, orr = idx & 63;
    u16 tmp[8];
#pragma unroll
    for (int j = 0; j < 8; ++j) tmp[j] = tile[orr + j][oc];
    *(v8s*)(out + (size_t)(c0 + oc) * R + (r0 + orr)) = *(v8s*)tmp;
  }
}

// ---------- batched Q/K/V projection GEMM; z==0 scales q; z==2 writes output TRANSPOSED ----------
__global__ __launch_bounds__(256) void gemm_qkv_k(const void* A0, const void* A1, const void* A2,
                                                  const u16* __restrict__ t0, const u16* __restrict__ t1,
                                                  const u16* __restrict__ t2,
                                                  const void* b0, const void* b1, const void* b2,
                                                  u16* __restrict__ qb, u16* __restrict__ kb,
                                                  u16* __restrict__ vtb) {
  __shared__ __align__(16) u16 As[64][72];
  __shared__ __align__(16) u16 Bs[64][72];
  bool f32 = detect_f32((const u16*)A0);
  int z = blockIdx.z;
  const void* Araw = (z == 0) ? A0 : (z == 1) ? A1 : A2;
  const u16* Bt    = (z == 0) ? t0 : (z == 1) ? t1 : t2;
  const void* bias = (z == 0) ? b0 : (z == 1) ? b1 : b2;
  const bool vt = (z == 2);
  const int i0 = blockIdx.x * 64, j0 = blockIdx.y * 64;
  const int t = threadIdx.x, w = t >> 6, l = t & 63, quad = l >> 4, l15 = l & 15;
  v4f acc[4] = {};
  for (int k0 = 0; k0 < 512; k0 += 64) {
#pragma unroll
    for (int rep = 0; rep < 2; ++rep) {
      int idx = (t + rep * 256) * 8;
      int r = idx >> 6, c = idx & 63;
      if (f32) {
        const float* sp = (const float*)Araw + (size_t)(i0 + r) * 512 + k0 + c;
        float4 fa = *(const float4*)sp, fb = *(const float4*)(sp + 4);
        uint4 q = make_uint4(pk_bf16(fa.x, fa.y), pk_bf16(fa.z, fa.w),
                             pk_bf16(fb.x, fb.y), pk_bf16(fb.z, fb.w));
        *(uint4*)&As[r][c] = q;
      } else {
        *(v8s*)&As[r][c] = *(const v8s*)((const u16*)Araw + (size_t)(i0 + r) * 512 + k0 + c);
      }
      *(v8s*)&Bs[r][c] = *(const v8s*)(Bt + (size_t)(j0 + r) * 512 + k0 + c);
    }
    __syncthreads();
    if (vt) {
#pragma unroll
      for (int h = 0; h < 2; ++h) {
        v8s a = *(const v8s*)&As[w * 16 + l15][h * 32 + quad * 8];
#pragma unroll
        for (int cb = 0; cb < 4; ++cb) {
          v8s b = *(const v8s*)&Bs[cb * 16 + l15][h * 32 + quad * 8];
          acc[cb] = __builtin_amdgcn_mfma_f32_16x16x32_bf16(b, a, acc[cb], 0, 0, 0);  // swapped -> C^T
        }
      }
    } else {
#pragma unroll
      for (int h = 0; h < 2; ++h) {
        v8s a = *(const v8s*)&As[w * 16 + l15][h * 32 + quad * 8];
#pragma unroll
        for (int cb = 0; cb < 4; ++cb) {
          v8s b = *(const v8s*)&Bs[cb * 16 + l15][h * 32 + quad * 8];
          acc[cb] = __builtin_amdgcn_mfma_f32_16x16x32_bf16(a, b, acc[cb], 0, 0, 0);
        }
      }
    }
    __syncthreads();
  }
  if (vt) {
#pragma unroll
    for (int cb = 0; cb < 4; ++cb) {
#pragma unroll
      for (int r = 0; r < 4; ++r) {
        int jj = j0 + cb * 16 + quad * 4 + r;
        int ii = i0 + w * 16 + l15;
        vtb[(size_t)jj * N_TOK + ii] = f2bf(acc[cb][r] + bias_ld(bias, jj, f32));
      }
    }
  } else {
    const float oscale = (z == 0) ? QSCALE : 1.0f;
    u16* C = (z == 0) ? qb : kb;
#pragma unroll
    for (int cb = 0; cb < 4; ++cb) {
      int col = j0 + cb * 16 + l15;
      float bv = bias_ld(bias, col, f32);
#pragma unroll
      for (int r = 0; r < 4; ++r) {
        int row = i0 + w * 16 + quad * 4 + r;
        C[(size_t)row * HD + col] = f2bf((acc[cb][r] + bv) * oscale);
      }
    }
  }
}

// ---------- fused attention (R1 structure; adjU8 + XCD-locality swizzle) ----------
// 1D grid of 1024 blocks. XCD = bid%8 (HW round-robin assumption, perf-only): all 32
// (head,split) blocks of one i0 land on one XCD -> its 4 adjU8 strips (4 x 512KB = 2MB)
// become L2-resident, cutting the 8x adjE re-read from L3 (the suspected invisible wall).
__global__ __launch_bounds__(256, 4) void attn_kernel(const u16* __restrict__ qb, const u16* __restrict__ kb,
                                                      const u16* __restrict__ vtb,
                                                      const unsigned char* __restrict__ adjU8,
                                                      u16* __restrict__ Opart, float* __restrict__ Lpart) {
  __shared__ __align__(16) u16 Ks[2][64 * 64];
  __shared__ __align__(16) u16 Vs[2][64 * 64];
  const int bid = blockIdx.x;
  const int g = bid >> 3;
  const int i0 = ((bid & 7) * 4 + (g & 3)) * QBLK;   // i0-index in [0,32): chunked per XCD
  const int hz = g >> 2;                              // [0,32)
  const int hh = hz & 7, z = hz >> 3;
  const int h64 = hh * 64;
  const int t = threadIdx.x, w = t >> 6, l = t & 63;
  const int il = l & 31, h2 = l >> 5, il7 = il & 7;
  const int iRow = i0 + w * 32 + il;           // this lane's q-row (C col = lane&31)

  // q as B-fragment: qf[c][j] = q[iRow][h64 + 16c + 8*h2 + j]
  v8s qf[4];
#pragma unroll
  for (int c = 0; c < 4; ++c)
    qf[c] = *(const v8s*)(qb + (size_t)iRow * HD + h64 + 16 * c + 8 * h2);

  const unsigned char* adjRow = adjU8 + (size_t)iRow * N_TOK + 4 * h2;

  // staging geometry: wave w stages rows 16w..16w+15 (2 glds of 8 rows each).
  // lane l -> row +(l>>3), LDS 16B-slot (l&7); source slot = (l&7) ^ (row&7)  [XOR swizzle]
  const int srow = l >> 3;
  const int scol = ((l & 7) ^ srow) * 8;       // u16 offset within row
  const int ldsrow = 16 * w;

  v16f oacc0 = {}, oacc1 = {};
  float lsum = 0.f;
  const int m_begin = z * (N_TOK / NSPLIT);

  // prologue: stage tile 0 into buf 0
#pragma unroll
  for (int n = 0; n < 2; ++n) {
    int r = ldsrow + 8 * n + srow;
    glds16(kb + (size_t)(m_begin + r) * HD + h64 + scol, &Ks[0][(ldsrow + 8 * n) * 64]);
    glds16(vtb + (size_t)(h64 + r) * N_TOK + m_begin + scol, &Vs[0][(ldsrow + 8 * n) * 64]);
  }
  __syncthreads();

  int buf = 0;
  for (int mt = 0; mt < NT; ++mt) {
    const int m0 = m_begin + mt * 64;
    if (mt + 1 < NT) {
      const int m1 = m0 + 64;
#pragma unroll
      for (int n = 0; n < 2; ++n) {
        int r = ldsrow + 8 * n + srow;
        glds16(kb + (size_t)(m1 + r) * HD + h64 + scol, &Ks[buf ^ 1][(ldsrow + 8 * n) * 64]);
        glds16(vtb + (size_t)(h64 + r) * N_TOK + m1 + scol, &Vs[buf ^ 1][(ldsrow + 8 * n) * 64]);
      }
    }
    const u16* Kb = &Ks[buf][0];
    const u16* Vb = &Vs[buf][0];

#pragma unroll
    for (int mh = 0; mh < 2; ++mh) {
      // adjU8 strip: av[rq] covers m = m0 + 32mh + 8rq + 4h2 + {0..3} (4 bytes)
      unsigned av[4];
#pragma unroll
      for (int rq = 0; rq < 4; ++rq)
        av[rq] = *(const unsigned*)(adjRow + m0 + 32 * mh + 8 * rq);

      // S^T quadrant: rows m = 32mh + il', cols i.  A=K frag row=lane&31, k=8*(lane>>5)+j
      v16f macc = {};
      __builtin_amdgcn_s_setprio(1);
#pragma unroll
      for (int c = 0; c < 4; ++c) {
        v8s kf = *(const v8s*)(Kb + (32 * mh + il) * 64 + (((2 * c + h2) ^ il7) * 8));
        macc = __builtin_amdgcn_mfma_f32_32x32x16_bf16(kf, qf[c], macc, 0, 0, 0);
      }
      __builtin_amdgcn_s_setprio(0);

      // elementwise: p = E * cubic(sigmoid(s));  E = 1 + enc*ER (u8 decode)
      float p[16];
#pragma unroll
      for (int rq = 0; rq < 4; ++rq) {
        unsigned ac = av[rq];
        float E0 = fmaf((float)(ac & 0xFFu),         ER, 1.0f);
        float E1 = fmaf((float)((ac >> 8) & 0xFFu),  ER, 1.0f);
        float E2 = fmaf((float)((ac >> 16) & 0xFFu), ER, 1.0f);
        float E3 = fmaf((float)(ac >> 24),           ER, 1.0f);
        float r0 = __builtin_amdgcn_rcpf(1.f + fast_exp2(-macc[4 * rq + 0]));
        float r1 = __builtin_amdgcn_rcpf(1.f + fast_exp2(-macc[4 * rq + 1]));
        float r2 = __builtin_amdgcn_rcpf(1.f + fast_exp2(-macc[4 * rq + 2]));
        float r3 = __builtin_amdgcn_rcpf(1.f + fast_exp2(-macc[4 * rq + 3]));
        float p0 = E0 * fmaf(fmaf(fmaf(EA3, r0, EA2), r0, EA1), r0, EA0);
        float p1 = E1 * fmaf(fmaf(fmaf(EA3, r1, EA2), r1, EA1), r1, EA0);
        float p2 = E2 * fmaf(fmaf(fmaf(EA3, r2, EA2), r2, EA1), r2, EA0);
        float p3 = E3 * fmaf(fmaf(fmaf(EA3, r3, EA2), r3, EA1), r3, EA0);
        lsum += (p0 + p1) + (p2 + p3);
        p[4 * rq + 0] = p0; p[4 * rq + 1] = p1; p[4 * rq + 2] = p2; p[4 * rq + 3] = p3;
      }

      // pack bf16 + permlane32_swap -> PV A-fragments (k = m within 16-chunk)
      v8s pf[2];
#pragma unroll
      for (int sub = 0; sub < 2; ++sub) {
        unsigned int u0 = pk_bf16(p[8 * sub + 0], p[8 * sub + 1]);
        unsigned int u1 = pk_bf16(p[8 * sub + 2], p[8 * sub + 3]);
        unsigned int u2 = pk_bf16(p[8 * sub + 4], p[8 * sub + 5]);
        unsigned int u3 = pk_bf16(p[8 * sub + 6], p[8 * sub + 7]);
        plswap(u0, u2); plswap(u1, u3);
        union { uint4 q; v8s v; } pu;
        pu.q = make_uint4(u0, u1, u2, u3);
        pf[sub] = pu.v;
      }

      // O[i][e] += P[i][m-chunk] @ V[m-chunk][e];  B=V frag from Vs[e][m] rows
      __builtin_amdgcn_s_setprio(1);
#pragma unroll
      for (int sub = 0; sub < 2; ++sub) {
        const int mc = 2 * mh + sub;
        v8s vf0 = *(const v8s*)(Vb + (il) * 64      + (((2 * mc + h2) ^ il7) * 8));
        v8s vf1 = *(const v8s*)(Vb + (32 + il) * 64 + (((2 * mc + h2) ^ il7) * 8));
        oacc0 = __builtin_amdgcn_mfma_f32_32x32x16_bf16(pf[sub], vf0, oacc0, 0, 0, 0);
        oacc1 = __builtin_amdgcn_mfma_f32_32x32x16_bf16(pf[sub], vf1, oacc1, 0, 0, 0);
      }
      __builtin_amdgcn_s_setprio(0);
    }
    __syncthreads();   // drains vmcnt (next buf staged) + protects buf overwrite
    buf ^= 1;
  }

  // lane holds half the m's for its i; partner (l^32) holds the other half
  lsum += __shfl_xor(lsum, 32);
  if (l < 32)
    Lpart[((size_t)z * N_TOK + i0 + 32 * w + il) * NH + hh] = lsum;

  // C layout: col = lane&31 (=e within 32-block), row = (r&3)+8(r>>2)+4h2 (=i_local)
#pragma unroll
  for (int r = 0; r < 16; ++r) {
    int i_local = (r & 3) + 8 * (r >> 2) + 4 * h2;
    size_t row = (size_t)z * N_TOK + i0 + 32 * w + i_local;
    u16* op = Opart + row * HD + h64 + il;
    op[0]  = f2bf(oacc0[r]);
    op[32] = f2bf(oacc1[r]);
  }
}

// ---------- final projection with fused split-combine: 256 blocks x 16 rows (full chip) ----------
__global__ __launch_bounds__(256) void gemm_bt(const u16* __restrict__ Opart, const float* __restrict__ Lpart,
                                               const u16* __restrict__ Bt, const void* bias,
                                               void* __restrict__ C, const u16* __restrict__ Qdet) {
  __shared__ __align__(16) u16 As[16][72];
  __shared__ __align__(16) u16 Bs[64][72];
  bool f32 = detect_f32(Qdet);
  const int i0 = blockIdx.x * 16;
  const int t = threadIdx.x, w = t >> 6, l = t & 63, quad = l >> 4, l15 = l & 15;
  v4f acc = {};
  for (int k0 = 0; k0 < 512; k0 += 64) {
    const int h = k0 >> 6;
    // A-panel: 16 rows x 64 cols, combined from NSPLIT partials + normalized
    if (t < 128) {
      int row = t >> 3, c8 = (t & 7) * 8;
      float lv = 0.f;
#pragma unroll
      for (int s = 0; s < NSPLIT; ++s) lv += Lpart[((size_t)s * N_TOK + i0 + row) * NH + h];
      float rl = __builtin_amdgcn_rcpf(lv);
      float vals[8] = {};
#pragma unroll
      for (int s = 0; s < NSPLIT; ++s) {
        v8s ov = *(const v8s*)(Opart + ((size_t)s * N_TOK + i0 + row) * HD + k0 + c8);
#pragma unroll
        for (int j = 0; j < 8; ++j) vals[j] += bf2f((u16)ov[j]);
      }
      uint4 q = make_uint4(pk_bf16(vals[0] * rl, vals[1] * rl), pk_bf16(vals[2] * rl, vals[3] * rl),
                           pk_bf16(vals[4] * rl, vals[5] * rl), pk_bf16(vals[6] * rl, vals[7] * rl));
      *(uint4*)&As[row][c8] = q;
    }
    // B-panel: 64 rows (output cols) x 64 k
#pragma unroll
    for (int rep = 0; rep < 2; ++rep) {
      int idx = (t + rep * 256) * 8;
      int r = idx >> 6, c = idx & 63;
      *(v8s*)&Bs[r][c] = *(const v8s*)(Bt + (size_t)r * 512 + k0 + c);
    }
    __syncthreads();
#pragma unroll
    for (int h2 = 0; h2 < 2; ++h2) {
      v8s a = *(const v8s*)&As[l15][h2 * 32 + quad * 8];
      v8s b = *(const v8s*)&Bs[w * 16 + l15][h2 * 32 + quad * 8];
      acc = __builtin_amdgcn_mfma_f32_16x16x32_bf16(a, b, acc, 0, 0, 0);
    }
    __syncthreads();
  }
  {
    int col = w * 16 + l15;
    float bv = bias_ld(bias, col, f32);
#pragma unroll
    for (int r = 0; r < 4; ++r) {
      int row = i0 + quad * 4 + r;
      float v = acc[r] + bv;
      size_t idx = (size_t)row * 64 + col;
      if (f32) ((float*)C)[idx] = v;
      else     ((u16*)C)[idx] = f2bf(v);
    }
  }
}

extern "C" void kernel_launch(void* const* d_in, const int* in_sizes, int n_in,
                              void* d_out, int out_size, void* d_ws, size_t ws_size,
                              hipStream_t stream) {
  (void)in_sizes; (void)n_in; (void)out_size; (void)ws_size;
  const void* Q   = d_in[0];
  const void* K   = d_in[1];
  const void* V   = d_in[2];
  const void* adj = d_in[3];
  const void* WQ  = d_in[4];
  const void* bQ  = d_in[5];
  const void* WK  = d_in[6];
  const void* bK  = d_in[7];
  const void* WV  = d_in[8];
  const void* bV  = d_in[9];
  const void* WO  = d_in[10];
  const void* bO  = d_in[11];
  const u16* Qdet = (const u16*)Q;

  char* p = (char*)d_ws;
  auto alloc = [&](size_t bytes) { char* r = p; p += (bytes + 255) & ~(size_t)255; return r; };
  const size_t SZ = (size_t)N_TOK * HD * 2;

  unsigned char* adjU8 = (unsigned char*)alloc((size_t)N_TOK * N_TOK);
  u16* qb      = (u16*)alloc(SZ);
  u16* kb      = (u16*)alloc(SZ);
  u16* vtb     = (u16*)alloc(SZ);
  u16* Opart   = (u16*)alloc((size_t)NSPLIT * SZ);
  float* Lpart = (float*)alloc((size_t)NSPLIT * N_TOK * NH * 4);
  u16* tQ      = (u16*)alloc((size_t)512 * 512 * 2);
  u16* tK      = (u16*)alloc((size_t)512 * 512 * 2);
  u16* tV      = (u16*)alloc((size_t)512 * 512 * 2);
  u16* tO      = (u16*)alloc((size_t)64 * 512 * 2);

  dim3 b256(256);
  conv_adjE_k<<<dim3(16384), b256, 0, stream>>>(adj, adjU8, Qdet);
  tr_w_k<<<dim3(8, 8, 4), b256, 0, stream>>>(WQ, WK, WV, WO, tQ, tK, tV, tO, Qdet);
  gemm_qkv_k<<<dim3(64, 8, 3), b256, 0, stream>>>(Q, K, V, tQ, tK, tV,
                                                  bQ, bK, bV, qb, kb, vtb);
  attn_kernel<<<dim3(1024), b256, 0, stream>>>(qb, kb, vtb, adjU8, Opart, Lpart);
  gemm_bt<<<dim3(256), b256, 0, stream>>>(Opart, Lpart, tO, bO, d_out, Qdet);
}

// Round 11
// 253.556 us; speedup vs baseline: 1.0652x; 1.0652x over previous
//
#include <hip/hip_runtime.h>
#include <hip/hip_bf16.h>

#define N_TOK  4096
#define HD     512   // H * 64
#define NH     8
#define NSPLIT 4
#define QBLK   128
#define NT     ((N_TOK / NSPLIT) / 64)

typedef short v8s __attribute__((ext_vector_type(8)));
typedef float v4f __attribute__((ext_vector_type(4)));
typedef float v16f __attribute__((ext_vector_type(16)));
typedef unsigned short u16;

#define QSCALE   0.18033688011112042f   // log2(e)/8  (folded into q at projection)
#define ADJ2     0.14426950408889634f   // 0.1*log2(e) (folded into E=exp2(ADJ2*adj))
// minimax cubic for e^x on [0,1]: max abs err ~5.5e-4 (<< bf16 P quantization 4e-3)
#define EA0 0.999410f
#define EA1 1.016220f
#define EA2 0.423120f
#define EA3 0.279120f

__device__ __forceinline__ float bf2f(u16 x) {
  union { unsigned int u; float f; } c; c.u = ((unsigned int)x) << 16; return c.f;
}
__device__ __forceinline__ u16 f2bf(float f) {
  union { float f; unsigned int u; } c; c.f = f;
  return (u16)((c.u + 0x7fffu + ((c.u >> 16) & 1u)) >> 16);
}
__device__ __forceinline__ float fast_exp2(float x) {
#if __has_builtin(__builtin_amdgcn_exp2f)
  return __builtin_amdgcn_exp2f(x);
#else
  return exp2f(x);
#endif
}
__device__ __forceinline__ unsigned int pk_bf16(float a, float b) {
  union { __hip_bfloat162 h; unsigned int u; } c;
  c.h = __float22bfloat162_rn(make_float2(a, b));
  return c.u;
}

// async global->LDS, 16B per lane; LDS dest is wave-uniform base + lane*16
typedef __attribute__((address_space(1))) const char gchar;
typedef __attribute__((address_space(3))) char lchar;
__device__ __forceinline__ void glds16(const void* g, void* l) {
  __builtin_amdgcn_global_load_lds((gchar*)g, (lchar*)l, 16, 0, 0);
}
// a' = [a_lo | b_lo], b' = [a_hi | b_hi]
__device__ __forceinline__ void plswap(unsigned int& a, unsigned int& b) {
  asm volatile("v_permlane32_swap_b32 %0, %1" : "+v"(a), "+v"(b));
}

// ---------- inline dtype detect: true -> inputs are fp32 (read from Q's first 128 u16) ----------
__device__ __forceinline__ bool detect_f32(const u16* __restrict__ q) {
  int l = threadIdx.x & 63;
  u16 e = q[2 * l];
  float x = bf2f(e);
  int ex = (e >> 7) & 0xFF;
  float ax = fabsf(x);
  bool ok = (ex != 0xFF) && (ax < 64.f) && (ax > 1e-30f);
  unsigned long long m = __ballot(ok);
  return __popcll(m) < 48;
}
__device__ __forceinline__ float bias_ld(const void* b, int i, bool f32) {
  return f32 ? ((const float*)b)[i] : bf2f(((const u16*)b)[i]);
}

// ---------- adjE = exp2(ADJ2*adj) in bf16 ----------
__global__ __launch_bounds__(256) void conv_adjE_k(const void* __restrict__ adj, u16* __restrict__ adjE,
                                                   const u16* __restrict__ Qdet) {
  bool f32 = detect_f32(Qdet);
  int i = blockIdx.x * 256 + threadIdx.x;   // 4 elems/thread, grid covers N*N/4 exactly
  float4 f;
  if (f32) {
    f = ((const float4*)adj)[i];
  } else {
    short4 v = ((const short4*)adj)[i];
    f.x = bf2f((u16)v.x); f.y = bf2f((u16)v.y); f.z = bf2f((u16)v.z); f.w = bf2f((u16)v.w);
  }
  unsigned int d0 = pk_bf16(fast_exp2(f.x * ADJ2), fast_exp2(f.y * ADJ2));
  unsigned int d1 = pk_bf16(fast_exp2(f.z * ADJ2), fast_exp2(f.w * ADJ2));
  ((uint2*)adjE)[i] = make_uint2(d0, d1);
}

// ---------- convert Q/K/V f32->bf16 ONCE (or copy if already bf16) ----------
// Removes the 8x-redundant per-j-block f32 load + pk_bf16 conversion inside gemm_qkv.
__global__ __launch_bounds__(256) void conv_qkv_k(const void* __restrict__ A0, const void* __restrict__ A1,
                                                  const void* __restrict__ A2,
                                                  u16* __restrict__ c0, u16* __restrict__ c1,
                                                  u16* __restrict__ c2, const u16* __restrict__ Qdet) {
  bool f32 = detect_f32(Qdet);
  int z = blockIdx.y;
  const void* in = (z == 0) ? A0 : (z == 1) ? A1 : A2;
  u16* out       = (z == 0) ? c0 : (z == 1) ? c1 : c2;
  int i = blockIdx.x * 256 + threadIdx.x;   // 8 elems/thread; grid.x = 4096*512/(256*8) = 1024
  if (f32) {
    const float* sp = (const float*)in + (size_t)i * 8;
    float4 a = *(const float4*)sp, b = *(const float4*)(sp + 4);
    uint4 q = make_uint4(pk_bf16(a.x, a.y), pk_bf16(a.z, a.w),
                         pk_bf16(b.x, b.y), pk_bf16(b.z, b.w));
    *(uint4*)(out + (size_t)i * 8) = q;
  } else {
    *(v8s*)(out + (size_t)i * 8) = *(const v8s*)((const u16*)in + (size_t)i * 8);
  }
}

// ---------- fused convert+transpose for all 4 weights: out[C][R] = bf16(in[R][C]) ----------
__global__ __launch_bounds__(256) void tr_w_k(const void* W0, const void* W1, const void* W2, const void* W3,
                                              u16* t0, u16* t1, u16* t2, u16* t3,
                                              const u16* __restrict__ Qdet) {
  bool f32 = detect_f32(Qdet);
  int z = blockIdx.z;
  const void* in; u16* out; int C;
  if (z == 0)      { in = W0; out = t0; C = 512; }
  else if (z == 1) { in = W1; out = t1; C = 512; }
  else if (z == 2) { in = W2; out = t2; C = 512; }
  else             { in = W3; out = t3; C = 64; if (blockIdx.y) return; }
  const int R = 512;
  __shared__ __align__(16) u16 tile[64][72];
  const int r0 = blockIdx.x * 64, c0 = blockIdx.y * 64;
  const int t = threadIdx.x;
#pragma unroll
  for (int rep = 0; rep < 2; ++rep) {
    int idx = (t + rep * 256) * 8;
    int r = idx >> 6, c = idx & 63;
    if (f32) {
      const float* sp = (const float*)in + (size_t)(r0 + r) * C + (c0 + c);
      float4 a = *(const float4*)sp, b = *(const float4*)(sp + 4);
      uint4 q = make_uint4(pk_bf16(a.x, a.y), pk_bf16(a.z, a.w),
                           pk_bf16(b.x, b.y), pk_bf16(b.z, b.w));
      *(uint4*)&tile[r][c] = q;
    } else {
      *(v8s*)&tile[r][c] = *(const v8s*)((const u16*)in + (size_t)(r0 + r) * C + (c0 + c));
    }
  }
  __syncthreads();
#pragma unroll
  for (int rep = 0; rep < 2; ++rep) {
    int idx = (t + rep * 256) * 8;
    int oc = idx >> 6, orr = idx & 63;
    u16 tmp[8];
#pragma unroll
    for (int j = 0; j < 8; ++j) tmp[j] = tile[orr + j][oc];
    *(v8s*)(out + (size_t)(c0 + oc) * R + (r0 + orr)) = *(v8s*)tmp;
  }
}

// ---------- batched Q/K/V projection GEMM (A pre-converted bf16); z==0 scales q; z==2 -> C^T ----------
__global__ __launch_bounds__(256) void gemm_qkv_k(const u16* __restrict__ c0, const u16* __restrict__ c1,
                                                  const u16* __restrict__ c2,
                                                  const u16* __restrict__ t0, const u16* __restrict__ t1,
                                                  const u16* __restrict__ t2,
                                                  const void* b0, const void* b1, const void* b2,
                                                  u16* __restrict__ qb, u16* __restrict__ kb,
                                                  u16* __restrict__ vtb, const u16* __restrict__ Qdet) {
  __shared__ __align__(16) u16 As[64][72];
  __shared__ __align__(16) u16 Bs[64][72];
  bool f32 = detect_f32(Qdet);
  int z = blockIdx.z;
  const u16* Abf = (z == 0) ? c0 : (z == 1) ? c1 : c2;
  const u16* Bt  = (z == 0) ? t0 : (z == 1) ? t1 : t2;
  const void* bias = (z == 0) ? b0 : (z == 1) ? b1 : b2;
  const bool vt = (z == 2);
  const int i0 = blockIdx.x * 64, j0 = blockIdx.y * 64;
  const int t = threadIdx.x, w = t >> 6, l = t & 63, quad = l >> 4, l15 = l & 15;
  v4f acc[4] = {};
  for (int k0 = 0; k0 < 512; k0 += 64) {
#pragma unroll
    for (int rep = 0; rep < 2; ++rep) {
      int idx = (t + rep * 256) * 8;
      int r = idx >> 6, c = idx & 63;
      *(v8s*)&As[r][c] = *(const v8s*)(Abf + (size_t)(i0 + r) * 512 + k0 + c);
      *(v8s*)&Bs[r][c] = *(const v8s*)(Bt + (size_t)(j0 + r) * 512 + k0 + c);
    }
    __syncthreads();
    if (vt) {
#pragma unroll
      for (int h = 0; h < 2; ++h) {
        v8s a = *(const v8s*)&As[w * 16 + l15][h * 32 + quad * 8];
#pragma unroll
        for (int cb = 0; cb < 4; ++cb) {
          v8s b = *(const v8s*)&Bs[cb * 16 + l15][h * 32 + quad * 8];
          acc[cb] = __builtin_amdgcn_mfma_f32_16x16x32_bf16(b, a, acc[cb], 0, 0, 0);  // swapped -> C^T
        }
      }
    } else {
#pragma unroll
      for (int h = 0; h < 2; ++h) {
        v8s a = *(const v8s*)&As[w * 16 + l15][h * 32 + quad * 8];
#pragma unroll
        for (int cb = 0; cb < 4; ++cb) {
          v8s b = *(const v8s*)&Bs[cb * 16 + l15][h * 32 + quad * 8];
          acc[cb] = __builtin_amdgcn_mfma_f32_16x16x32_bf16(a, b, acc[cb], 0, 0, 0);
        }
      }
    }
    __syncthreads();
  }
  if (vt) {
#pragma unroll
    for (int cb = 0; cb < 4; ++cb) {
#pragma unroll
      for (int r = 0; r < 4; ++r) {
        int jj = j0 + cb * 16 + quad * 4 + r;
        int ii = i0 + w * 16 + l15;
        vtb[(size_t)jj * N_TOK + ii] = f2bf(acc[cb][r] + bias_ld(bias, jj, f32));
      }
    }
  } else {
    const float oscale = (z == 0) ? QSCALE : 1.0f;
    u16* C = (z == 0) ? qb : kb;
#pragma unroll
    for (int cb = 0; cb < 4; ++cb) {
      int col = j0 + cb * 16 + l15;
      float bv = bias_ld(bias, col, f32);
#pragma unroll
      for (int r = 0; r < 4; ++r) {
        int row = i0 + w * 16 + quad * 4 + r;
        C[(size_t)row * HD + col] = f2bf((acc[cb][r] + bv) * oscale);
      }
    }
  }
}

// ---------- fused attention (R1/R9 known-good, byte-identical) ----------
__global__ __launch_bounds__(256, 4) void attn_kernel(const u16* __restrict__ qb, const u16* __restrict__ kb,
                                                      const u16* __restrict__ vtb, const u16* __restrict__ adjE,
                                                      u16* __restrict__ Opart, float* __restrict__ Lpart) {
  __shared__ __align__(16) u16 Ks[2][64 * 64];
  __shared__ __align__(16) u16 Vs[2][64 * 64];
  const int i0 = blockIdx.x * QBLK, h64 = blockIdx.y * 64, z = blockIdx.z;
  const int t = threadIdx.x, w = t >> 6, l = t & 63;
  const int il = l & 31, h2 = l >> 5, il7 = il & 7;
  const int iRow = i0 + w * 32 + il;           // this lane's q-row (C col = lane&31)

  // q as B-fragment: qf[c][j] = q[iRow][h64 + 16c + 8*h2 + j]
  v8s qf[4];
#pragma unroll
  for (int c = 0; c < 4; ++c)
    qf[c] = *(const v8s*)(qb + (size_t)iRow * HD + h64 + 16 * c + 8 * h2);

  const u16* adjRow = adjE + (size_t)iRow * N_TOK + 4 * h2;

  // staging geometry: wave w stages rows 16w..16w+15 (2 glds of 8 rows each).
  // lane l -> row +(l>>3), LDS 16B-slot (l&7); source slot = (l&7) ^ (row&7)  [XOR swizzle]
  const int srow = l >> 3;
  const int scol = ((l & 7) ^ srow) * 8;       // u16 offset within row
  const int ldsrow = 16 * w;

  v16f oacc0 = {}, oacc1 = {};
  float lsum = 0.f;
  const int m_begin = z * (N_TOK / NSPLIT);

  // prologue: stage tile 0 into buf 0
#pragma unroll
  for (int n = 0; n < 2; ++n) {
    int r = ldsrow + 8 * n + srow;
    glds16(kb + (size_t)(m_begin + r) * HD + h64 + scol, &Ks[0][(ldsrow + 8 * n) * 64]);
    glds16(vtb + (size_t)(h64 + r) * N_TOK + m_begin + scol, &Vs[0][(ldsrow + 8 * n) * 64]);
  }
  __syncthreads();

  int buf = 0;
  for (int mt = 0; mt < NT; ++mt) {
    const int m0 = m_begin + mt * 64;
    if (mt + 1 < NT) {
      const int m1 = m0 + 64;
#pragma unroll
      for (int n = 0; n < 2; ++n) {
        int r = ldsrow + 8 * n + srow;
        glds16(kb + (size_t)(m1 + r) * HD + h64 + scol, &Ks[buf ^ 1][(ldsrow + 8 * n) * 64]);
        glds16(vtb + (size_t)(h64 + r) * N_TOK + m1 + scol, &Vs[buf ^ 1][(ldsrow + 8 * n) * 64]);
      }
    }
    const u16* Kb = &Ks[buf][0];
    const u16* Vb = &Vs[buf][0];

#pragma unroll
    for (int mh = 0; mh < 2; ++mh) {
      // adjE strip: av[rq] covers m = m0 + 32mh + 8rq + 4h2 + {0..3}  (matches C-reg layout)
      uint2 av[4];
#pragma unroll
      for (int rq = 0; rq < 4; ++rq)
        av[rq] = *(const uint2*)(adjRow + m0 + 32 * mh + 8 * rq);

      // S^T quadrant: rows m = 32mh + il', cols i.  A=K frag row=lane&31, k=8*(lane>>5)+j
      v16f macc = {};
      __builtin_amdgcn_s_setprio(1);
#pragma unroll
      for (int c = 0; c < 4; ++c) {
        v8s kf = *(const v8s*)(Kb + (32 * mh + il) * 64 + (((2 * c + h2) ^ il7) * 8));
        macc = __builtin_amdgcn_mfma_f32_32x32x16_bf16(kf, qf[c], macc, 0, 0, 0);
      }
      __builtin_amdgcn_s_setprio(0);

      // elementwise: p = E * cubic(sigmoid(s));  reg r <-> m_local = (r&3)+8(r>>2)+4h2
      float p[16];
#pragma unroll
      for (int rq = 0; rq < 4; ++rq) {
        union { unsigned int u; float f; } e0, e1, e2, e3;
        e0.u = av[rq].x << 16; e1.u = av[rq].x & 0xFFFF0000u;
        e2.u = av[rq].y << 16; e3.u = av[rq].y & 0xFFFF0000u;
        float r0 = __builtin_amdgcn_rcpf(1.f + fast_exp2(-macc[4 * rq + 0]));
        float r1 = __builtin_amdgcn_rcpf(1.f + fast_exp2(-macc[4 * rq + 1]));
        float r2 = __builtin_amdgcn_rcpf(1.f + fast_exp2(-macc[4 * rq + 2]));
        float r3 = __builtin_amdgcn_rcpf(1.f + fast_exp2(-macc[4 * rq + 3]));
        float p0 = e0.f * fmaf(fmaf(fmaf(EA3, r0, EA2), r0, EA1), r0, EA0);
        float p1 = e1.f * fmaf(fmaf(fmaf(EA3, r1, EA2), r1, EA1), r1, EA0);
        float p2 = e2.f * fmaf(fmaf(fmaf(EA3, r2, EA2), r2, EA1), r2, EA0);
        float p3 = e3.f * fmaf(fmaf(fmaf(EA3, r3, EA2), r3, EA1), r3, EA0);
        lsum += (p0 + p1) + (p2 + p3);
        p[4 * rq + 0] = p0; p[4 * rq + 1] = p1; p[4 * rq + 2] = p2; p[4 * rq + 3] = p3;
      }

      // pack bf16 + permlane32_swap -> PV A-fragments (k = m within 16-chunk)
      v8s pf[2];
#pragma unroll
      for (int sub = 0; sub < 2; ++sub) {
        unsigned int u0 = pk_bf16(p[8 * sub + 0], p[8 * sub + 1]);
        unsigned int u1 = pk_bf16(p[8 * sub + 2], p[8 * sub + 3]);
        unsigned int u2 = pk_bf16(p[8 * sub + 4], p[8 * sub + 5]);
        unsigned int u3 = pk_bf16(p[8 * sub + 6], p[8 * sub + 7]);
        plswap(u0, u2); plswap(u1, u3);
        union { uint4 q; v8s v; } pu;
        pu.q = make_uint4(u0, u1, u2, u3);
        pf[sub] = pu.v;
      }

      // O[i][e] += P[i][m-chunk] @ V[m-chunk][e];  B=V frag from Vs[e][m] rows
      __builtin_amdgcn_s_setprio(1);
#pragma unroll
      for (int sub = 0; sub < 2; ++sub) {
        const int mc = 2 * mh + sub;
        v8s vf0 = *(const v8s*)(Vb + (il) * 64      + (((2 * mc + h2) ^ il7) * 8));
        v8s vf1 = *(const v8s*)(Vb + (32 + il) * 64 + (((2 * mc + h2) ^ il7) * 8));
        oacc0 = __builtin_amdgcn_mfma_f32_32x32x16_bf16(pf[sub], vf0, oacc0, 0, 0, 0);
        oacc1 = __builtin_amdgcn_mfma_f32_32x32x16_bf16(pf[sub], vf1, oacc1, 0, 0, 0);
      }
      __builtin_amdgcn_s_setprio(0);
    }
    __syncthreads();   // drains vmcnt (next buf staged) + protects buf overwrite
    buf ^= 1;
  }

  // lane holds half the m's for its i; partner (l^32) holds the other half
  lsum += __shfl_xor(lsum, 32);
  if (l < 32)
    Lpart[((size_t)z * N_TOK + i0 + 32 * w + il) * NH + blockIdx.y] = lsum;

  // C layout: col = lane&31 (=e within 32-block), row = (r&3)+8(r>>2)+4h2 (=i_local)
#pragma unroll
  for (int r = 0; r < 16; ++r) {
    int i_local = (r & 3) + 8 * (r >> 2) + 4 * h2;
    size_t row = (size_t)z * N_TOK + i0 + 32 * w + i_local;
    u16* op = Opart + row * HD + h64 + il;
    op[0]  = f2bf(oacc0[r]);
    op[32] = f2bf(oacc1[r]);
  }
}

// ---------- final projection with fused split-combine: 256 blocks x 16 rows (full chip) ----------
__global__ __launch_bounds__(256) void gemm_bt(const u16* __restrict__ Opart, const float* __restrict__ Lpart,
                                               const u16* __restrict__ Bt, const void* bias,
                                               void* __restrict__ C, const u16* __restrict__ Qdet) {
  __shared__ __align__(16) u16 As[16][72];
  __shared__ __align__(16) u16 Bs[64][72];
  bool f32 = detect_f32(Qdet);
  const int i0 = blockIdx.x * 16;
  const int t = threadIdx.x, w = t >> 6, l = t & 63, quad = l >> 4, l15 = l & 15;
  v4f acc = {};
  for (int k0 = 0; k0 < 512; k0 += 64) {
    const int h = k0 >> 6;
    // A-panel: 16 rows x 64 cols, combined from NSPLIT partials + normalized
    if (t < 128) {
      int row = t >> 3, c8 = (t & 7) * 8;
      float lv = 0.f;
#pragma unroll
      for (int s = 0; s < NSPLIT; ++s) lv += Lpart[((size_t)s * N_TOK + i0 + row) * NH + h];
      float rl = __builtin_amdgcn_rcpf(lv);
      float vals[8] = {};
#pragma unroll
      for (int s = 0; s < NSPLIT; ++s) {
        v8s ov = *(const v8s*)(Opart + ((size_t)s * N_TOK + i0 + row) * HD + k0 + c8);
#pragma unroll
        for (int j = 0; j < 8; ++j) vals[j] += bf2f((u16)ov[j]);
      }
      uint4 q = make_uint4(pk_bf16(vals[0] * rl, vals[1] * rl), pk_bf16(vals[2] * rl, vals[3] * rl),
                           pk_bf16(vals[4] * rl, vals[5] * rl), pk_bf16(vals[6] * rl, vals[7] * rl));
      *(uint4*)&As[row][c8] = q;
    }
    // B-panel: 64 rows (output cols) x 64 k
#pragma unroll
    for (int rep = 0; rep < 2; ++rep) {
      int idx = (t + rep * 256) * 8;
      int r = idx >> 6, c = idx & 63;
      *(v8s*)&Bs[r][c] = *(const v8s*)(Bt + (size_t)r * 512 + k0 + c);
    }
    __syncthreads();
#pragma unroll
    for (int h2 = 0; h2 < 2; ++h2) {
      v8s a = *(const v8s*)&As[l15][h2 * 32 + quad * 8];
      v8s b = *(const v8s*)&Bs[w * 16 + l15][h2 * 32 + quad * 8];
      acc = __builtin_amdgcn_mfma_f32_16x16x32_bf16(a, b, acc, 0, 0, 0);
    }
    __syncthreads();
  }
  {
    int col = w * 16 + l15;
    float bv = bias_ld(bias, col, f32);
#pragma unroll
    for (int r = 0; r < 4; ++r) {
      int row = i0 + quad * 4 + r;
      float v = acc[r] + bv;
      size_t idx = (size_t)row * 64 + col;
      if (f32) ((float*)C)[idx] = v;
      else     ((u16*)C)[idx] = f2bf(v);
    }
  }
}

extern "C" void kernel_launch(void* const* d_in, const int* in_sizes, int n_in,
                              void* d_out, int out_size, void* d_ws, size_t ws_size,
                              hipStream_t stream) {
  (void)in_sizes; (void)n_in; (void)out_size; (void)ws_size;
  const void* Q   = d_in[0];
  const void* K   = d_in[1];
  const void* V   = d_in[2];
  const void* adj = d_in[3];
  const void* WQ  = d_in[4];
  const void* bQ  = d_in[5];
  const void* WK  = d_in[6];
  const void* bK  = d_in[7];
  const void* WV  = d_in[8];
  const void* bV  = d_in[9];
  const void* WO  = d_in[10];
  const void* bO  = d_in[11];
  const u16* Qdet = (const u16*)Q;

  char* p = (char*)d_ws;
  auto alloc = [&](size_t bytes) { char* r = p; p += (bytes + 255) & ~(size_t)255; return r; };
  const size_t SZ = (size_t)N_TOK * HD * 2;

  u16* adjE    = (u16*)alloc((size_t)N_TOK * N_TOK * 2);
  u16* qb      = (u16*)alloc(SZ);
  u16* kb      = (u16*)alloc(SZ);
  u16* vtb     = (u16*)alloc(SZ);
  u16* Opart   = (u16*)alloc((size_t)NSPLIT * SZ);
  float* Lpart = (float*)alloc((size_t)NSPLIT * N_TOK * NH * 4);
  u16* tQ      = (u16*)alloc((size_t)512 * 512 * 2);
  u16* tK      = (u16*)alloc((size_t)512 * 512 * 2);
  u16* tV      = (u16*)alloc((size_t)512 * 512 * 2);
  u16* tO      = (u16*)alloc((size_t)64 * 512 * 2);
  u16* Qc      = (u16*)alloc(SZ);
  u16* Kc      = (u16*)alloc(SZ);
  u16* Vc      = (u16*)alloc(SZ);

  dim3 b256(256);
  conv_adjE_k<<<dim3(16384), b256, 0, stream>>>(adj, adjE, Qdet);
  conv_qkv_k<<<dim3(1024, 3), b256, 0, stream>>>(Q, K, V, Qc, Kc, Vc, Qdet);
  tr_w_k<<<dim3(8, 8, 4), b256, 0, stream>>>(WQ, WK, WV, WO, tQ, tK, tV, tO, Qdet);
  gemm_qkv_k<<<dim3(64, 8, 3), b256, 0, stream>>>(Qc, Kc, Vc, tQ, tK, tV,
                                                  bQ, bK, bV, qb, kb, vtb, Qdet);
  attn_kernel<<<dim3(N_TOK / QBLK, NH, NSPLIT), b256, 0, stream>>>(qb, kb, vtb, adjE, Opart, Lpart);
  gemm_bt<<<dim3(256), b256, 0, stream>>>(Opart, Lpart, tO, bO, d_out, Qdet);
}

// Round 12
// 249.259 us; speedup vs baseline: 1.0835x; 1.0172x over previous
//
#include <hip/hip_runtime.h>
#include <hip/hip_bf16.h>

#define N_TOK  4096
#define HD     512   // H * 64
#define NH     8
#define NSPLIT 4
#define QBLK   128
#define NT     ((N_TOK / NSPLIT) / 64)

typedef short v8s __attribute__((ext_vector_type(8)));
typedef float v4f __attribute__((ext_vector_type(4)));
typedef float v16f __attribute__((ext_vector_type(16)));
typedef unsigned short u16;

#define QSCALE   0.18033688011112042f   // log2(e)/8  (folded into q at projection)
#define ADJ2     0.14426950408889634f   // 0.1*log2(e) (folded into E=exp2(ADJ2*adj))
// minimax cubic for e^x on [0,1]: max abs err ~5.5e-4 (<< bf16 P quantization 4e-3)
#define EA0 0.999410f
#define EA1 1.016220f
#define EA2 0.423120f
#define EA3 0.279120f

__device__ __forceinline__ float bf2f(u16 x) {
  union { unsigned int u; float f; } c; c.u = ((unsigned int)x) << 16; return c.f;
}
__device__ __forceinline__ u16 f2bf(float f) {
  union { float f; unsigned int u; } c; c.f = f;
  return (u16)((c.u + 0x7fffu + ((c.u >> 16) & 1u)) >> 16);
}
__device__ __forceinline__ float fast_exp2(float x) {
#if __has_builtin(__builtin_amdgcn_exp2f)
  return __builtin_amdgcn_exp2f(x);
#else
  return exp2f(x);
#endif
}
__device__ __forceinline__ unsigned int pk_bf16(float a, float b) {
  union { __hip_bfloat162 h; unsigned int u; } c;
  c.h = __float22bfloat162_rn(make_float2(a, b));
  return c.u;
}

// async global->LDS, 16B per lane; LDS dest is wave-uniform base + lane*16
typedef __attribute__((address_space(1))) const char gchar;
typedef __attribute__((address_space(3))) char lchar;
__device__ __forceinline__ void glds16(const void* g, void* l) {
  __builtin_amdgcn_global_load_lds((gchar*)g, (lchar*)l, 16, 0, 0);
}
// a' = [a_lo | b_lo], b' = [a_hi | b_hi]
__device__ __forceinline__ void plswap(unsigned int& a, unsigned int& b) {
  asm volatile("v_permlane32_swap_b32 %0, %1" : "+v"(a), "+v"(b));
}

// ---------- inline dtype detect: true -> inputs are fp32 (read from Q's first 128 u16) ----------
__device__ __forceinline__ bool detect_f32(const u16* __restrict__ q) {
  int l = threadIdx.x & 63;
  u16 e = q[2 * l];
  float x = bf2f(e);
  int ex = (e >> 7) & 0xFF;
  float ax = fabsf(x);
  bool ok = (ex != 0xFF) && (ax < 64.f) && (ax > 1e-30f);
  unsigned long long m = __ballot(ok);
  return __popcll(m) < 48;
}
__device__ __forceinline__ float bias_ld(const void* b, int i, bool f32) {
  return f32 ? ((const float*)b)[i] : bf2f(((const u16*)b)[i]);
}

// ---------- adjE = exp2(ADJ2*adj) in bf16 ----------
__global__ __launch_bounds__(256) void conv_adjE_k(const void* __restrict__ adj, u16* __restrict__ adjE,
                                                   const u16* __restrict__ Qdet) {
  bool f32 = detect_f32(Qdet);
  int i = blockIdx.x * 256 + threadIdx.x;   // 4 elems/thread, grid covers N*N/4 exactly
  float4 f;
  if (f32) {
    f = ((const float4*)adj)[i];
  } else {
    short4 v = ((const short4*)adj)[i];
    f.x = bf2f((u16)v.x); f.y = bf2f((u16)v.y); f.z = bf2f((u16)v.z); f.w = bf2f((u16)v.w);
  }
  unsigned int d0 = pk_bf16(fast_exp2(f.x * ADJ2), fast_exp2(f.y * ADJ2));
  unsigned int d1 = pk_bf16(fast_exp2(f.z * ADJ2), fast_exp2(f.w * ADJ2));
  ((uint2*)adjE)[i] = make_uint2(d0, d1);
}

// ---------- convert Q/K/V f32->bf16 ONCE (or copy if already bf16) ----------
__global__ __launch_bounds__(256) void conv_qkv_k(const void* __restrict__ A0, const void* __restrict__ A1,
                                                  const void* __restrict__ A2,
                                                  u16* __restrict__ c0, u16* __restrict__ c1,
                                                  u16* __restrict__ c2, const u16* __restrict__ Qdet) {
  bool f32 = detect_f32(Qdet);
  int z = blockIdx.y;
  const void* in = (z == 0) ? A0 : (z == 1) ? A1 : A2;
  u16* out       = (z == 0) ? c0 : (z == 1) ? c1 : c2;
  int i = blockIdx.x * 256 + threadIdx.x;   // 8 elems/thread; grid.x = 4096*512/(256*8) = 1024
  if (f32) {
    const float* sp = (const float*)in + (size_t)i * 8;
    float4 a = *(const float4*)sp, b = *(const float4*)(sp + 4);
    uint4 q = make_uint4(pk_bf16(a.x, a.y), pk_bf16(a.z, a.w),
                         pk_bf16(b.x, b.y), pk_bf16(b.z, b.w));
    *(uint4*)(out + (size_t)i * 8) = q;
  } else {
    *(v8s*)(out + (size_t)i * 8) = *(const v8s*)((const u16*)in + (size_t)i * 8);
  }
}

// ---------- fused convert+transpose for all 4 weights: out[C][R] = bf16(in[R][C]) ----------
__global__ __launch_bounds__(256) void tr_w_k(const void* W0, const void* W1, const void* W2, const void* W3,
                                              u16* t0, u16* t1, u16* t2, u16* t3,
                                              const u16* __restrict__ Qdet) {
  bool f32 = detect_f32(Qdet);
  int z = blockIdx.z;
  const void* in; u16* out; int C;
  if (z == 0)      { in = W0; out = t0; C = 512; }
  else if (z == 1) { in = W1; out = t1; C = 512; }
  else if (z == 2) { in = W2; out = t2; C = 512; }
  else             { in = W3; out = t3; C = 64; if (blockIdx.y) return; }
  const int R = 512;
  __shared__ __align__(16) u16 tile[64][72];
  const int r0 = blockIdx.x * 64, c0 = blockIdx.y * 64;
  const int t = threadIdx.x;
#pragma unroll
  for (int rep = 0; rep < 2; ++rep) {
    int idx = (t + rep * 256) * 8;
    int r = idx >> 6, c = idx & 63;
    if (f32) {
      const float* sp = (const float*)in + (size_t)(r0 + r) * C + (c0 + c);
      float4 a = *(const float4*)sp, b = *(const float4*)(sp + 4);
      uint4 q = make_uint4(pk_bf16(a.x, a.y), pk_bf16(a.z, a.w),
                           pk_bf16(b.x, b.y), pk_bf16(b.z, b.w));
      *(uint4*)&tile[r][c] = q;
    } else {
      *(v8s*)&tile[r][c] = *(const v8s*)((const u16*)in + (size_t)(r0 + r) * C + (c0 + c));
    }
  }
  __syncthreads();
#pragma unroll
  for (int rep = 0; rep < 2; ++rep) {
    int idx = (t + rep * 256) * 8;
    int oc = idx >> 6, orr = idx & 63;
    u16 tmp[8];
#pragma unroll
    for (int j = 0; j < 8; ++j) tmp[j] = tile[orr + j][oc];
    *(v8s*)(out + (size_t)(c0 + oc) * R + (r0 + orr)) = *(v8s*)tmp;
  }
}

// ---------- batched Q/K/V projection GEMM, attn-style glds16 double-buffered staging ----------
// A pre-converted bf16 (R11). Per k-tile: stage k+1 via 4 global_load_lds (XOR-swizzled
// source, linear LDS dest), compute k from the other buffer, ONE __syncthreads.
// Fragment reads apply the same XOR on the slot index. z==0 scales q; z==2 writes C^T.
__global__ __launch_bounds__(256) void gemm_qkv_k(const u16* __restrict__ c0, const u16* __restrict__ c1,
                                                  const u16* __restrict__ c2,
                                                  const u16* __restrict__ t0, const u16* __restrict__ t1,
                                                  const u16* __restrict__ t2,
                                                  const void* b0, const void* b1, const void* b2,
                                                  u16* __restrict__ qb, u16* __restrict__ kb,
                                                  u16* __restrict__ vtb, const u16* __restrict__ Qdet) {
  __shared__ __align__(16) u16 As[2][64 * 64];
  __shared__ __align__(16) u16 Bs[2][64 * 64];
  bool f32 = detect_f32(Qdet);
  int z = blockIdx.z;
  const u16* Abf = (z == 0) ? c0 : (z == 1) ? c1 : c2;
  const u16* Bt  = (z == 0) ? t0 : (z == 1) ? t1 : t2;
  const void* bias = (z == 0) ? b0 : (z == 1) ? b1 : b2;
  const bool vt = (z == 2);
  const int i0 = blockIdx.x * 64, j0 = blockIdx.y * 64;
  const int t = threadIdx.x, w = t >> 6, l = t & 63, quad = l >> 4, l15 = l & 15;
  // staging geometry (attn-verified): wave w stages rows 16w..16w+15; lane l -> row +(l>>3),
  // LDS 16B-slot (l&7); source slot = (l&7)^(row&7) [XOR swizzle, same XOR on read]
  const int srow = l >> 3;
  const int scol = ((l & 7) ^ srow) * 8;       // u16 offset within row
  const int ldsrow = 16 * w;

#define STG(BUF, K0)                                                         \
  _Pragma("unroll") for (int n_ = 0; n_ < 2; ++n_) {                         \
    int r_ = ldsrow + 8 * n_ + srow;                                         \
    glds16(Abf + (size_t)(i0 + r_) * 512 + (K0) + scol,                      \
           (u16*)As[BUF] + (ldsrow + 8 * n_) * 64);                          \
    glds16(Bt + (size_t)(j0 + r_) * 512 + (K0) + scol,                       \
           (u16*)Bs[BUF] + (ldsrow + 8 * n_) * 64);                          \
  }

  v4f acc[4] = {};
  STG(0, 0)
  __syncthreads();
  int buf = 0;
  for (int kt = 0; kt < 8; ++kt) {
    if (kt + 1 < 8) {
      STG(buf ^ 1, (kt + 1) * 64)
    }
    const u16* Ab = As[buf];
    const u16* Bb = Bs[buf];
    const int arow = w * 16 + l15;
#pragma unroll
    for (int h = 0; h < 2; ++h) {
      v8s a = *(const v8s*)(Ab + arow * 64 + (((h * 4 + quad) ^ (arow & 7)) * 8));
      if (vt) {
#pragma unroll
        for (int cb = 0; cb < 4; ++cb) {
          const int brow = cb * 16 + l15;
          v8s b = *(const v8s*)(Bb + brow * 64 + (((h * 4 + quad) ^ (brow & 7)) * 8));
          acc[cb] = __builtin_amdgcn_mfma_f32_16x16x32_bf16(b, a, acc[cb], 0, 0, 0);  // swapped -> C^T
        }
      } else {
#pragma unroll
        for (int cb = 0; cb < 4; ++cb) {
          const int brow = cb * 16 + l15;
          v8s b = *(const v8s*)(Bb + brow * 64 + (((h * 4 + quad) ^ (brow & 7)) * 8));
          acc[cb] = __builtin_amdgcn_mfma_f32_16x16x32_bf16(a, b, acc[cb], 0, 0, 0);
        }
      }
    }
    __syncthreads();   // drains vmcnt (next buf staged) + protects buf overwrite
    buf ^= 1;
  }
#undef STG
  if (vt) {
#pragma unroll
    for (int cb = 0; cb < 4; ++cb) {
#pragma unroll
      for (int r = 0; r < 4; ++r) {
        int jj = j0 + cb * 16 + quad * 4 + r;
        int ii = i0 + w * 16 + l15;
        vtb[(size_t)jj * N_TOK + ii] = f2bf(acc[cb][r] + bias_ld(bias, jj, f32));
      }
    }
  } else {
    const float oscale = (z == 0) ? QSCALE : 1.0f;
    u16* C = (z == 0) ? qb : kb;
#pragma unroll
    for (int cb = 0; cb < 4; ++cb) {
      int col = j0 + cb * 16 + l15;
      float bv = bias_ld(bias, col, f32);
#pragma unroll
      for (int r = 0; r < 4; ++r) {
        int row = i0 + w * 16 + quad * 4 + r;
        C[(size_t)row * HD + col] = f2bf((acc[cb][r] + bv) * oscale);
      }
    }
  }
}

// ---------- fused attention (R1/R9 known-good, byte-identical) ----------
__global__ __launch_bounds__(256, 4) void attn_kernel(const u16* __restrict__ qb, const u16* __restrict__ kb,
                                                      const u16* __restrict__ vtb, const u16* __restrict__ adjE,
                                                      u16* __restrict__ Opart, float* __restrict__ Lpart) {
  __shared__ __align__(16) u16 Ks[2][64 * 64];
  __shared__ __align__(16) u16 Vs[2][64 * 64];
  const int i0 = blockIdx.x * QBLK, h64 = blockIdx.y * 64, z = blockIdx.z;
  const int t = threadIdx.x, w = t >> 6, l = t & 63;
  const int il = l & 31, h2 = l >> 5, il7 = il & 7;
  const int iRow = i0 + w * 32 + il;           // this lane's q-row (C col = lane&31)

  // q as B-fragment: qf[c][j] = q[iRow][h64 + 16c + 8*h2 + j]
  v8s qf[4];
#pragma unroll
  for (int c = 0; c < 4; ++c)
    qf[c] = *(const v8s*)(qb + (size_t)iRow * HD + h64 + 16 * c + 8 * h2);

  const u16* adjRow = adjE + (size_t)iRow * N_TOK + 4 * h2;

  // staging geometry: wave w stages rows 16w..16w+15 (2 glds of 8 rows each).
  // lane l -> row +(l>>3), LDS 16B-slot (l&7); source slot = (l&7) ^ (row&7)  [XOR swizzle]
  const int srow = l >> 3;
  const int scol = ((l & 7) ^ srow) * 8;       // u16 offset within row
  const int ldsrow = 16 * w;

  v16f oacc0 = {}, oacc1 = {};
  float lsum = 0.f;
  const int m_begin = z * (N_TOK / NSPLIT);

  // prologue: stage tile 0 into buf 0
#pragma unroll
  for (int n = 0; n < 2; ++n) {
    int r = ldsrow + 8 * n + srow;
    glds16(kb + (size_t)(m_begin + r) * HD + h64 + scol, &Ks[0][(ldsrow + 8 * n) * 64]);
    glds16(vtb + (size_t)(h64 + r) * N_TOK + m_begin + scol, &Vs[0][(ldsrow + 8 * n) * 64]);
  }
  __syncthreads();

  int buf = 0;
  for (int mt = 0; mt < NT; ++mt) {
    const int m0 = m_begin + mt * 64;
    if (mt + 1 < NT) {
      const int m1 = m0 + 64;
#pragma unroll
      for (int n = 0; n < 2; ++n) {
        int r = ldsrow + 8 * n + srow;
        glds16(kb + (size_t)(m1 + r) * HD + h64 + scol, &Ks[buf ^ 1][(ldsrow + 8 * n) * 64]);
        glds16(vtb + (size_t)(h64 + r) * N_TOK + m1 + scol, &Vs[buf ^ 1][(ldsrow + 8 * n) * 64]);
      }
    }
    const u16* Kb = &Ks[buf][0];
    const u16* Vb = &Vs[buf][0];

#pragma unroll
    for (int mh = 0; mh < 2; ++mh) {
      // adjE strip: av[rq] covers m = m0 + 32mh + 8rq + 4h2 + {0..3}  (matches C-reg layout)
      uint2 av[4];
#pragma unroll
      for (int rq = 0; rq < 4; ++rq)
        av[rq] = *(const uint2*)(adjRow + m0 + 32 * mh + 8 * rq);

      // S^T quadrant: rows m = 32mh + il', cols i.  A=K frag row=lane&31, k=8*(lane>>5)+j
      v16f macc = {};
      __builtin_amdgcn_s_setprio(1);
#pragma unroll
      for (int c = 0; c < 4; ++c) {
        v8s kf = *(const v8s*)(Kb + (32 * mh + il) * 64 + (((2 * c + h2) ^ il7) * 8));
        macc = __builtin_amdgcn_mfma_f32_32x32x16_bf16(kf, qf[c], macc, 0, 0, 0);
      }
      __builtin_amdgcn_s_setprio(0);

      // elementwise: p = E * cubic(sigmoid(s));  reg r <-> m_local = (r&3)+8(r>>2)+4h2
      float p[16];
#pragma unroll
      for (int rq = 0; rq < 4; ++rq) {
        union { unsigned int u; float f; } e0, e1, e2, e3;
        e0.u = av[rq].x << 16; e1.u = av[rq].x & 0xFFFF0000u;
        e2.u = av[rq].y << 16; e3.u = av[rq].y & 0xFFFF0000u;
        float r0 = __builtin_amdgcn_rcpf(1.f + fast_exp2(-macc[4 * rq + 0]));
        float r1 = __builtin_amdgcn_rcpf(1.f + fast_exp2(-macc[4 * rq + 1]));
        float r2 = __builtin_amdgcn_rcpf(1.f + fast_exp2(-macc[4 * rq + 2]));
        float r3 = __builtin_amdgcn_rcpf(1.f + fast_exp2(-macc[4 * rq + 3]));
        float p0 = e0.f * fmaf(fmaf(fmaf(EA3, r0, EA2), r0, EA1), r0, EA0);
        float p1 = e1.f * fmaf(fmaf(fmaf(EA3, r1, EA2), r1, EA1), r1, EA0);
        float p2 = e2.f * fmaf(fmaf(fmaf(EA3, r2, EA2), r2, EA1), r2, EA0);
        float p3 = e3.f * fmaf(fmaf(fmaf(EA3, r3, EA2), r3, EA1), r3, EA0);
        lsum += (p0 + p1) + (p2 + p3);
        p[4 * rq + 0] = p0; p[4 * rq + 1] = p1; p[4 * rq + 2] = p2; p[4 * rq + 3] = p3;
      }

      // pack bf16 + permlane32_swap -> PV A-fragments (k = m within 16-chunk)
      v8s pf[2];
#pragma unroll
      for (int sub = 0; sub < 2; ++sub) {
        unsigned int u0 = pk_bf16(p[8 * sub + 0], p[8 * sub + 1]);
        unsigned int u1 = pk_bf16(p[8 * sub + 2], p[8 * sub + 3]);
        unsigned int u2 = pk_bf16(p[8 * sub + 4], p[8 * sub + 5]);
        unsigned int u3 = pk_bf16(p[8 * sub + 6], p[8 * sub + 7]);
        plswap(u0, u2); plswap(u1, u3);
        union { uint4 q; v8s v; } pu;
        pu.q = make_uint4(u0, u1, u2, u3);
        pf[sub] = pu.v;
      }

      // O[i][e] += P[i][m-chunk] @ V[m-chunk][e];  B=V frag from Vs[e][m] rows
      __builtin_amdgcn_s_setprio(1);
#pragma unroll
      for (int sub = 0; sub < 2; ++sub) {
        const int mc = 2 * mh + sub;
        v8s vf0 = *(const v8s*)(Vb + (il) * 64      + (((2 * mc + h2) ^ il7) * 8));
        v8s vf1 = *(const v8s*)(Vb + (32 + il) * 64 + (((2 * mc + h2) ^ il7) * 8));
        oacc0 = __builtin_amdgcn_mfma_f32_32x32x16_bf16(pf[sub], vf0, oacc0, 0, 0, 0);
        oacc1 = __builtin_amdgcn_mfma_f32_32x32x16_bf16(pf[sub], vf1, oacc1, 0, 0, 0);
      }
      __builtin_amdgcn_s_setprio(0);
    }
    __syncthreads();   // drains vmcnt (next buf staged) + protects buf overwrite
    buf ^= 1;
  }

  // lane holds half the m's for its i; partner (l^32) holds the other half
  lsum += __shfl_xor(lsum, 32);
  if (l < 32)
    Lpart[((size_t)z * N_TOK + i0 + 32 * w + il) * NH + blockIdx.y] = lsum;

  // C layout: col = lane&31 (=e within 32-block), row = (r&3)+8(r>>2)+4h2 (=i_local)
#pragma unroll
  for (int r = 0; r < 16; ++r) {
    int i_local = (r & 3) + 8 * (r >> 2) + 4 * h2;
    size_t row = (size_t)z * N_TOK + i0 + 32 * w + i_local;
    u16* op = Opart + row * HD + h64 + il;
    op[0]  = f2bf(oacc0[r]);
    op[32] = f2bf(oacc1[r]);
  }
}

// ---------- final projection with fused split-combine: 256 blocks x 16 rows (full chip) ----------
__global__ __launch_bounds__(256) void gemm_bt(const u16* __restrict__ Opart, const float* __restrict__ Lpart,
                                               const u16* __restrict__ Bt, const void* bias,
                                               void* __restrict__ C, const u16* __restrict__ Qdet) {
  __shared__ __align__(16) u16 As[16][72];
  __shared__ __align__(16) u16 Bs[64][72];
  bool f32 = detect_f32(Qdet);
  const int i0 = blockIdx.x * 16;
  const int t = threadIdx.x, w = t >> 6, l = t & 63, quad = l >> 4, l15 = l & 15;
  v4f acc = {};
  for (int k0 = 0; k0 < 512; k0 += 64) {
    const int h = k0 >> 6;
    // A-panel: 16 rows x 64 cols, combined from NSPLIT partials + normalized
    if (t < 128) {
      int row = t >> 3, c8 = (t & 7) * 8;
      float lv = 0.f;
#pragma unroll
      for (int s = 0; s < NSPLIT; ++s) lv += Lpart[((size_t)s * N_TOK + i0 + row) * NH + h];
      float rl = __builtin_amdgcn_rcpf(lv);
      float vals[8] = {};
#pragma unroll
      for (int s = 0; s < NSPLIT; ++s) {
        v8s ov = *(const v8s*)(Opart + ((size_t)s * N_TOK + i0 + row) * HD + k0 + c8);
#pragma unroll
        for (int j = 0; j < 8; ++j) vals[j] += bf2f((u16)ov[j]);
      }
      uint4 q = make_uint4(pk_bf16(vals[0] * rl, vals[1] * rl), pk_bf16(vals[2] * rl, vals[3] * rl),
                           pk_bf16(vals[4] * rl, vals[5] * rl), pk_bf16(vals[6] * rl, vals[7] * rl));
      *(uint4*)&As[row][c8] = q;
    }
    // B-panel: 64 rows (output cols) x 64 k
#pragma unroll
    for (int rep = 0; rep < 2; ++rep) {
      int idx = (t + rep * 256) * 8;
      int r = idx >> 6, c = idx & 63;
      *(v8s*)&Bs[r][c] = *(const v8s*)(Bt + (size_t)r * 512 + k0 + c);
    }
    __syncthreads();
#pragma unroll
    for (int h2 = 0; h2 < 2; ++h2) {
      v8s a = *(const v8s*)&As[l15][h2 * 32 + quad * 8];
      v8s b = *(const v8s*)&Bs[w * 16 + l15][h2 * 32 + quad * 8];
      acc = __builtin_amdgcn_mfma_f32_16x16x32_bf16(a, b, acc, 0, 0, 0);
    }
    __syncthreads();
  }
  {
    int col = w * 16 + l15;
    float bv = bias_ld(bias, col, f32);
#pragma unroll
    for (int r = 0; r < 4; ++r) {
      int row = i0 + quad * 4 + r;
      float v = acc[r] + bv;
      size_t idx = (size_t)row * 64 + col;
      if (f32) ((float*)C)[idx] = v;
      else     ((u16*)C)[idx] = f2bf(v);
    }
  }
}

extern "C" void kernel_launch(void* const* d_in, const int* in_sizes, int n_in,
                              void* d_out, int out_size, void* d_ws, size_t ws_size,
                              hipStream_t stream) {
  (void)in_sizes; (void)n_in; (void)out_size; (void)ws_size;
  const void* Q   = d_in[0];
  const void* K   = d_in[1];
  const void* V   = d_in[2];
  const void* adj = d_in[3];
  const void* WQ  = d_in[4];
  const void* bQ  = d_in[5];
  const void* WK  = d_in[6];
  const void* bK  = d_in[7];
  const void* WV  = d_in[8];
  const void* bV  = d_in[9];
  const void* WO  = d_in[10];
  const void* bO  = d_in[11];
  const u16* Qdet = (const u16*)Q;

  char* p = (char*)d_ws;
  auto alloc = [&](size_t bytes) { char* r = p; p += (bytes + 255) & ~(size_t)255; return r; };
  const size_t SZ = (size_t)N_TOK * HD * 2;

  u16* adjE    = (u16*)alloc((size_t)N_TOK * N_TOK * 2);
  u16* qb      = (u16*)alloc(SZ);
  u16* kb      = (u16*)alloc(SZ);
  u16* vtb     = (u16*)alloc(SZ);
  u16* Opart   = (u16*)alloc((size_t)NSPLIT * SZ);
  float* Lpart = (float*)alloc((size_t)NSPLIT * N_TOK * NH * 4);
  u16* tQ      = (u16*)alloc((size_t)512 * 512 * 2);
  u16* tK      = (u16*)alloc((size_t)512 * 512 * 2);
  u16* tV      = (u16*)alloc((size_t)512 * 512 * 2);
  u16* tO      = (u16*)alloc((size_t)64 * 512 * 2);
  u16* Qc      = (u16*)alloc(SZ);
  u16* Kc      = (u16*)alloc(SZ);
  u16* Vc      = (u16*)alloc(SZ);

  dim3 b256(256);
  conv_adjE_k<<<dim3(16384), b256, 0, stream>>>(adj, adjE, Qdet);
  conv_qkv_k<<<dim3(1024, 3), b256, 0, stream>>>(Q, K, V, Qc, Kc, Vc, Qdet);
  tr_w_k<<<dim3(8, 8, 4), b256, 0, stream>>>(WQ, WK, WV, WO, tQ, tK, tV, tO, Qdet);
  gemm_qkv_k<<<dim3(64, 8, 3), b256, 0, stream>>>(Qc, Kc, Vc, tQ, tK, tV,
                                                  bQ, bK, bV, qb, kb, vtb, Qdet);
  attn_kernel<<<dim3(N_TOK / QBLK, NH, NSPLIT), b256, 0, stream>>>(qb, kb, vtb, adjE, Opart, Lpart);
  gemm_bt<<<dim3(256), b256, 0, stream>>>(Opart, Lpart, tO, bO, d_out, Qdet);
}